// Round 1
// baseline (486.118 us; speedup 1.0000x reference)
//
#include <hip/hip_runtime.h>
#include <hip/hip_bf16.h>

// FFNPCCNorm: out[n,o] = max( (xc[n]·wc[o]) / (|xc[n]| |wc[o]|), 1e-10 ) + bias[o]
// with xc = x - rowmean(x), wc = w - rowmean(w).
// Identity: sum(wc[o,:]) == 0  =>  xc·wc == x·wc. Fold 1/|wc| into bf16 B,
// fold 1/|xc| into bf16 A during LDS staging. GEMM via bf16 MFMA 16x16x32.

#define K_DIM 256
#define N_OUT 256
#define BM 64
#define LDS_STRIDE 264   // 256 + 8 bf16 pad: breaks 512B stride -> 2-way bank alias (free)

typedef __attribute__((ext_vector_type(8))) __bf16 bf16x8;
typedef __attribute__((ext_vector_type(4))) float f32x4;

__device__ __forceinline__ unsigned short f2bf(float f) {
    union { float f; unsigned u; } v; v.f = f;
    unsigned r = v.u + 0x7FFFu + ((v.u >> 16) & 1u);   // RNE
    return (unsigned short)(r >> 16);
}

// One wave per weight row: compute wc = (w - mean) * rsqrt(sum(wc^2)), store bf16.
__global__ __launch_bounds__(64) void prep_w(const float* __restrict__ w,
                                             unsigned short* __restrict__ wcb) {
    int o = blockIdx.x;        // 256 rows
    int lane = threadIdx.x;    // 64 lanes, 4 floats each
    f32x4 v = *((const f32x4*)(w + (size_t)o * K_DIM) + lane);
    float s  = v.x + v.y + v.z + v.w;
    float s2 = v.x*v.x + v.y*v.y + v.z*v.z + v.w*v.w;
#pragma unroll
    for (int off = 32; off >= 1; off >>= 1) {
        s  += __shfl_xor(s,  off);
        s2 += __shfl_xor(s2, off);
    }
    float mean  = s * (1.0f / 256.0f);
    float var   = s2 - s * mean;                 // sum((w-mean)^2)
    float scale = rsqrtf(fmaxf(var, 1e-30f));
    ushort4 b;
    b.x = f2bf((v.x - mean) * scale);
    b.y = f2bf((v.y - mean) * scale);
    b.z = f2bf((v.z - mean) * scale);
    b.w = f2bf((v.w - mean) * scale);
    *(ushort4*)(wcb + (size_t)o * K_DIM + lane * 4) = b;
}

__global__ __launch_bounds__(256, 2) void pcc_gemm(const float* __restrict__ x,
                                                   const unsigned short* __restrict__ wcb,
                                                   const float* __restrict__ bias,
                                                   float* __restrict__ out) {
    __shared__ unsigned short xs[BM * LDS_STRIDE];

    const int t    = threadIdx.x;
    const int wave = t >> 6;
    const int lane = t & 63;
    const size_t row0 = (size_t)blockIdx.x * BM;

    const float* xbase = x + row0 * K_DIM;

    // ---- Stage: each wave loads one full row per iter (fully coalesced 1KB),
    // reduces sum/sumsq across 64 lanes, scales row to unit norm, stores bf16.
#pragma unroll 2
    for (int it = 0; it < 16; ++it) {
        const int row = it * 4 + wave;
        f32x4 v = *((const f32x4*)(xbase + (size_t)row * K_DIM) + lane);
        float s  = v.x + v.y + v.z + v.w;
        float s2 = v.x*v.x + v.y*v.y + v.z*v.z + v.w*v.w;
#pragma unroll
        for (int off = 32; off >= 1; off >>= 1) {
            s  += __shfl_xor(s,  off);
            s2 += __shfl_xor(s2, off);
        }
        float var = s2 - s * s * (1.0f / 256.0f);   // sum(xc^2), fp32 from original x
        float inv = rsqrtf(fmaxf(var, 1e-30f));
        ushort4 b;
        b.x = f2bf(v.x * inv);
        b.y = f2bf(v.y * inv);
        b.z = f2bf(v.z * inv);
        b.w = f2bf(v.w * inv);
        *(ushort4*)(xs + row * LDS_STRIDE + lane * 4) = b;
    }
    __syncthreads();

    // ---- MFMA: wave w owns rows[0..63] x cols[n0..n0+63] = 4x4 tiles of 16x16.
    const int l15  = lane & 15;
    const int quad = lane >> 4;
    const int n0   = wave * 64;

    f32x4 acc[4][4];
#pragma unroll
    for (int mi = 0; mi < 4; ++mi)
#pragma unroll
        for (int ni = 0; ni < 4; ++ni)
            acc[mi][ni] = (f32x4){0.f, 0.f, 0.f, 0.f};

    const unsigned short* wbase = wcb + (size_t)n0 * K_DIM + quad * 8;

#pragma unroll
    for (int ks = 0; ks < 8; ++ks) {
        bf16x8 a[4], b[4];
#pragma unroll
        for (int mi = 0; mi < 4; ++mi)
            a[mi] = *(const bf16x8*)(xs + (mi * 16 + l15) * LDS_STRIDE + ks * 32 + quad * 8);
#pragma unroll
        for (int ni = 0; ni < 4; ++ni)
            b[ni] = *(const bf16x8*)(wbase + (size_t)(ni * 16 + l15) * K_DIM + ks * 32);
#pragma unroll
        for (int mi = 0; mi < 4; ++mi)
#pragma unroll
            for (int ni = 0; ni < 4; ++ni)
                acc[mi][ni] = __builtin_amdgcn_mfma_f32_16x16x32_bf16(a[mi], b[ni], acc[mi][ni], 0, 0, 0);
    }

    // ---- Epilogue: D layout col = lane&15, row = quad*4 + reg.
    float bv[4];
#pragma unroll
    for (int ni = 0; ni < 4; ++ni) bv[ni] = bias[n0 + ni * 16 + l15];

    float* obase = out + row0 * N_OUT;
#pragma unroll
    for (int mi = 0; mi < 4; ++mi) {
#pragma unroll
        for (int r = 0; r < 4; ++r) {
            const int orow = mi * 16 + quad * 4 + r;
            float* op = obase + (size_t)orow * N_OUT + n0 + l15;
#pragma unroll
            for (int ni = 0; ni < 4; ++ni)
                op[ni * 16] = fmaxf(acc[mi][ni][r], 1e-10f) + bv[ni];
        }
    }
}

extern "C" void kernel_launch(void* const* d_in, const int* in_sizes, int n_in,
                              void* d_out, int out_size, void* d_ws, size_t ws_size,
                              hipStream_t stream) {
    const float* x    = (const float*)d_in[0];   // [262144, 256]
    const float* w    = (const float*)d_in[1];   // [256, 256]
    const float* bias = (const float*)d_in[2];   // [256]
    float* out = (float*)d_out;                  // [262144, 256]
    unsigned short* wcb = (unsigned short*)d_ws; // 128 KB bf16 wc (scaled)

    prep_w<<<256, 64, 0, stream>>>(w, wcb);
    pcc_gemm<<<262144 / BM, 256, 0, stream>>>(x, wcb, bias, out);
}

// Round 2
// 474.810 us; speedup vs baseline: 1.0238x; 1.0238x over previous
//
#include <hip/hip_runtime.h>
#include <hip/hip_bf16.h>

// FFNPCCNorm: out[n,o] = max( (xc[n]·wc[o]) / (|xc[n]| |wc[o]|), 1e-10 ) + bias[o]
// with xc = x - rowmean(x), wc = w - rowmean(w).
// Identities used:
//   sum(wc[o,:]) == 0       =>  xc·wc == x·wc  (no need to center x for GEMM)
//   1/|wc| folded into bf16 B (prep_w);  1/|xc| applied in the epilogue (fp32).
// GEMM via bf16 MFMA 16x16x32. A staged raw-bf16 in LDS; row norms in fp32.

#define K_DIM 256
#define N_OUT 256
#define BM 64
#define LDS_STRIDE 264   // 256 + 8 bf16 pad: group-stride 33 (odd) spreads b128 reads

typedef __attribute__((ext_vector_type(8))) __bf16 bf16x8;
typedef __attribute__((ext_vector_type(8))) unsigned short u16x8;
typedef __attribute__((ext_vector_type(4))) float f32x4;

__device__ __forceinline__ unsigned short f2bf(float f) {
    union { float f; unsigned u; } v; v.f = f;
    unsigned r = v.u + 0x7FFFu + ((v.u >> 16) & 1u);   // RNE
    return (unsigned short)(r >> 16);
}

// One wave per weight row: wc = (w - mean) * rsqrt(sum(wc^2)), stored bf16.
__global__ __launch_bounds__(64) void prep_w(const float* __restrict__ w,
                                             unsigned short* __restrict__ wcb) {
    int o = blockIdx.x;        // 256 rows
    int lane = threadIdx.x;    // 64 lanes, 4 floats each
    f32x4 v = *((const f32x4*)(w + (size_t)o * K_DIM) + lane);
    float s  = v.x + v.y + v.z + v.w;
    float s2 = v.x*v.x + v.y*v.y + v.z*v.z + v.w*v.w;
#pragma unroll
    for (int off = 32; off >= 1; off >>= 1) {
        s  += __shfl_xor(s,  off);
        s2 += __shfl_xor(s2, off);
    }
    float mean  = s * (1.0f / 256.0f);
    float var   = s2 - s * mean;                 // sum((w-mean)^2)
    float scale = rsqrtf(fmaxf(var, 1e-30f));
    ushort4 b;
    b.x = f2bf((v.x - mean) * scale);
    b.y = f2bf((v.y - mean) * scale);
    b.z = f2bf((v.z - mean) * scale);
    b.w = f2bf((v.w - mean) * scale);
    *(ushort4*)(wcb + (size_t)o * K_DIM + lane * 4) = b;
}

__global__ __launch_bounds__(256, 4) void pcc_gemm(const float* __restrict__ x,
                                                   const unsigned short* __restrict__ wcb,
                                                   const float* __restrict__ bias,
                                                   float* __restrict__ out) {
    __shared__ unsigned short xs[BM * LDS_STRIDE];
    __shared__ float nrm[BM];

    const int t    = threadIdx.x;
    const int wave = t >> 6;
    const int lane = t & 63;
    const int l15  = lane & 15;
    const int q    = lane >> 4;
    const size_t row0 = (size_t)blockIdx.x * BM;

    // ---- Stage: wave stages rows [wave*16, wave*16+16). Each lane owns one
    // contiguous quarter-row (64 floats): all 16 dwordx4 loads issue back-to-back
    // (full MLP), raw bf16 goes to LDS immediately (no wait on the reduction),
    // and the row reduce needs only 2 shuffle levels (across quads).
    const int srow = wave * 16 + l15;
    const float* rp = x + (row0 + srow) * K_DIM + q * 64;

    f32x4 v[16];
#pragma unroll
    for (int j = 0; j < 16; ++j) v[j] = ((const f32x4*)rp)[j];

    // bias for this wave's output columns — issue early to hide latency
    const int n0 = wave * 64;
    float bv[4];
#pragma unroll
    for (int ni = 0; ni < 4; ++ni) bv[ni] = bias[n0 + ni * 16 + l15];

    unsigned short* wp = xs + srow * LDS_STRIDE + q * 64;
#pragma unroll
    for (int j = 0; j < 8; ++j) {
        u16x8 p;
        p[0] = f2bf(v[2*j].x);   p[1] = f2bf(v[2*j].y);
        p[2] = f2bf(v[2*j].z);   p[3] = f2bf(v[2*j].w);
        p[4] = f2bf(v[2*j+1].x); p[5] = f2bf(v[2*j+1].y);
        p[6] = f2bf(v[2*j+1].z); p[7] = f2bf(v[2*j+1].w);
        *(u16x8*)(wp + j * 8) = p;
    }

    float s = 0.f, s2 = 0.f;
#pragma unroll
    for (int j = 0; j < 16; ++j) {
        s += v[j].x + v[j].y + v[j].z + v[j].w;
        s2 = fmaf(v[j].x, v[j].x, s2);
        s2 = fmaf(v[j].y, v[j].y, s2);
        s2 = fmaf(v[j].z, v[j].z, s2);
        s2 = fmaf(v[j].w, v[j].w, s2);
    }
    s  += __shfl_xor(s, 16);  s  += __shfl_xor(s, 32);
    s2 += __shfl_xor(s2, 16); s2 += __shfl_xor(s2, 32);
    float var = s2 - s * s * (1.0f / 256.0f);   // sum(xc^2), fp32 from raw x
    float inv = rsqrtf(fmaxf(var, 1e-30f));
    if (q == 0) nrm[srow] = inv;
    __syncthreads();

    // ---- MFMA: wave owns rows[0..63] x cols[n0..n0+63] = 4x4 tiles of 16x16x32.
    f32x4 acc[4][4];
#pragma unroll
    for (int mi = 0; mi < 4; ++mi)
#pragma unroll
        for (int ni = 0; ni < 4; ++ni)
            acc[mi][ni] = (f32x4){0.f, 0.f, 0.f, 0.f};

    const unsigned short* wbase = wcb + (size_t)n0 * K_DIM + q * 8;

#pragma unroll
    for (int ks = 0; ks < 8; ++ks) {
        bf16x8 a[4], b[4];
#pragma unroll
        for (int mi = 0; mi < 4; ++mi)
            a[mi] = *(const bf16x8*)(xs + (mi * 16 + l15) * LDS_STRIDE + ks * 32 + q * 8);
#pragma unroll
        for (int ni = 0; ni < 4; ++ni)
            b[ni] = *(const bf16x8*)(wbase + (size_t)(ni * 16 + l15) * K_DIM + ks * 32);
#pragma unroll
        for (int mi = 0; mi < 4; ++mi)
#pragma unroll
            for (int ni = 0; ni < 4; ++ni)
                acc[mi][ni] = __builtin_amdgcn_mfma_f32_16x16x32_bf16(a[mi], b[ni], acc[mi][ni], 0, 0, 0);
    }

    // ---- Epilogue: D layout col = lane&15, row = q*4 + reg.
    // corr = acc * inv_row; clamp; + bias.
    float invv[4][4];
#pragma unroll
    for (int mi = 0; mi < 4; ++mi)
#pragma unroll
        for (int r = 0; r < 4; ++r)
            invv[mi][r] = nrm[mi * 16 + q * 4 + r];

    float* obase = out + row0 * N_OUT;
#pragma unroll
    for (int mi = 0; mi < 4; ++mi) {
#pragma unroll
        for (int r = 0; r < 4; ++r) {
            const int orow = mi * 16 + q * 4 + r;
            float* op = obase + (size_t)orow * N_OUT + n0 + l15;
#pragma unroll
            for (int ni = 0; ni < 4; ++ni)
                op[ni * 16] = fmaxf(acc[mi][ni][r] * invv[mi][r], 1e-10f) + bv[ni];
        }
    }
}

extern "C" void kernel_launch(void* const* d_in, const int* in_sizes, int n_in,
                              void* d_out, int out_size, void* d_ws, size_t ws_size,
                              hipStream_t stream) {
    const float* x    = (const float*)d_in[0];   // [262144, 256]
    const float* w    = (const float*)d_in[1];   // [256, 256]
    const float* bias = (const float*)d_in[2];   // [256]
    float* out = (float*)d_out;                  // [262144, 256]
    unsigned short* wcb = (unsigned short*)d_ws; // 128 KB bf16 wc (scaled)

    prep_w<<<256, 64, 0, stream>>>(w, wcb);
    pcc_gemm<<<262144 / BM, 256, 0, stream>>>(x, wcb, bias, out);
}